// Round 12
// baseline (144.317 us; speedup 1.0000x reference)
//
#include <hip/hip_runtime.h>

// SSIM loss over [8,8,3,256,256] fp32.
// R19 (PASS, 128us): MFMA conv rewrite, mfma_f32_16x16x32_f16 (m89-verified
//   layouts). R20 (FAIL 4.3e-2): ds_read_b64_tr_b16 used with WAVE-UNIFORM
//   address -- per m156 "uniform addr reads the same value (no internal
//   lane offset)"; the m162 lane formula assumes PER-LANE addressing. All
//   lanes fetched the same 8 bytes -> garbage horizontal A-frags.
// R21: tr-read ELIMINATED via operand swap. Vertical computed transposed:
//   mfma(data_frag, wf_v) -- then D (m89: col=lane&15, row=4g+reg) hands
//   each lane V[img row m][img cols c0+4g .. +3] = 4 consecutive pcols at
//   fixed row -> V store into ROW-MAJOR plane = one aligned b64 write
//   (16/wave vs R19's 64 scalar ds_write_u16), and the horizontal A-frag
//   is a plain aligned b64 load == R19's already-validated horizontal
//   structure (data-as-A, wf-as-B). Every fragment role here passed in R19.
//   Alignment: front pad = 8 pcols (not 5) so stores are 8B-aligned;
//   horizontal weights shift to gw[k-m-3]. V stride 552B -> m*138 mod 32
//   all-distinct = conflict-free. RTE packing (R19 numerics) restored.
//   Kept from R20: atomicAdd fusion (one add per block; block 0 adds +1),
//   dead-row skip (k>=26 has all-zero weights -> no global load).
// R9 scar: cvt_pkrtz returns half2 directly -- bit-cast.
// Rule-20: all arrays fully unrolled / compile-time indexed.

typedef _Float16 h2 __attribute__((ext_vector_type(2)));
typedef _Float16 half4 __attribute__((ext_vector_type(4)));
typedef _Float16 half8 __attribute__((ext_vector_type(8)));
typedef float f32x4 __attribute__((ext_vector_type(4)));
typedef __fp16 fp16v2 __attribute__((ext_vector_type(2)));

#define WSZ 11
#define RAD 5
#define IMH 256
#define IMW 256
#define BROWS 16                     // output rows per block
#define NBANDS (IMH / BROWS)         // 16
#define NPLANES 192                  // 8*8*3
#define NGRID (NPLANES * NBANDS)     // 3072 blocks
#define WPB 4                        // waves per block
#define NPIXF (192.0f * 256.0f * 256.0f)

// Input planes (s,d): col-major [256 col][36 k-slot] f16, stride 72B.
#define CSTRIDE 72
#define INPLANE (256 * CSTRIDE)      // 18432 B per channel
// V planes (4 ch): row-major [16 row][276 pcol] f16, stride 552B.
// pcol = img_col + 8 (front pad 8 for b64 alignment; data pcols 8..263).
#define VROWSTRIDE 552
#define VPLANE (16 * VROWSTRIDE)     // 8832 B per channel (4ch = 35328)
#define SMEM_BYTES 36864             // max(2*INPLANE, 4*VPLANE)

// ---- packed fp16 ops ----
__device__ __forceinline__ h2 pk_fma16(h2 a, h2 b, h2 c) {
    h2 d;
    asm("v_pk_fma_f16 %0, %1, %2, %3" : "=v"(d) : "v"(a), "v"(b), "v"(c));
    return d;
}
__device__ __forceinline__ h2 pk_mul16(h2 a, h2 b) {
    h2 d;
    asm("v_pk_mul_f16 %0, %1, %2" : "=v"(d) : "v"(a), "v"(b));
    return d;
}
__device__ __forceinline__ h2 pk_add16(h2 a, h2 b) {
    h2 d;
    asm("v_pk_add_f16 %0, %1, %2" : "=v"(d) : "v"(a), "v"(b));
    return d;
}
__device__ __forceinline__ h2 pk_min16(h2 a, h2 b) {
    h2 d;
    asm("v_pk_min_f16 %0, %1, %2" : "=v"(d) : "v"(a), "v"(b));
    return d;
}
__device__ __forceinline__ h2 pk_max16(h2 a, h2 b) {
    h2 d;
    asm("v_pk_max_f16 %0, %1, %2" : "=v"(d) : "v"(a), "v"(b));
    return d;
}

union H2U { h2 h; unsigned u; };
__device__ __forceinline__ unsigned h2u(h2 v) { H2U x; x.h = v; return x.u; }

__device__ __forceinline__ h2 splat16(float s) {
    _Float16 t = (_Float16)s;
    return (h2){t, t};
}
__device__ __forceinline__ h2 zero16() { return (h2){(_Float16)0, (_Float16)0}; }

// clip to [0,1] in fp16 after pack (range-equivalent for this data).
__device__ __forceinline__ h2 clip_pack(float a, float b, h2 Z, h2 O) {
    fp16v2 r = __builtin_amdgcn_cvt_pkrtz(a, b);
    h2 v = __builtin_bit_cast(h2, r);
    return pk_min16(pk_max16(v, Z), O);
}
// pack two f32 -> u32 of 2 f16 with ROUND-TO-NEAREST (R19 numerics).
__device__ __forceinline__ unsigned pack2_rte(float a, float b) {
    fp16v2 r;
    r[0] = (__fp16)a;
    r[1] = (__fp16)b;
    return __builtin_bit_cast(unsigned, r);
}

// v_perm_b32 pair builders: {a.f16[0], b.f16[0]} and {a.f16[1], b.f16[1]}.
__device__ __forceinline__ unsigned lo_pair(h2 a, h2 b) {
    return __builtin_amdgcn_perm(h2u(b), h2u(a), 0x05040100u);
}
__device__ __forceinline__ unsigned hi_pair(h2 a, h2 b) {
    return __builtin_amdgcn_perm(h2u(b), h2u(a), 0x07060302u);
}

// gfx950 f16 MFMA, K=32, HW-verified layouts (m89 family).
__device__ __forceinline__ f32x4 mfma32(half8 a, half8 b, f32x4 c) {
    return __builtin_amdgcn_mfma_f32_16x16x32_f16(a, b, c, 0, 0, 0);
}

__device__ __forceinline__ half8 cat8(half4 lo, half4 hi) {
    half8 r;
    r[0] = lo[0]; r[1] = lo[1]; r[2] = lo[2]; r[3] = lo[3];
    r[4] = hi[0]; r[5] = hi[1]; r[6] = hi[2]; r[7] = hi[3];
    return r;
}

// elementwise square of a half4 (2x v_pk_mul_f16)
__device__ __forceinline__ half4 sq4(half4 v) {
    union { half4 v4; h2 h[2]; } u, r;
    u.v4 = v;
    r.h[0] = pk_mul16(u.h[0], u.h[0]);
    r.h[1] = pk_mul16(u.h[1], u.h[1]);
    return r.v4;
}

// Gaussian(sigma=1.5) tap weight gw[dd], zero outside [0,10].
__device__ __forceinline__ float gweight(int dd) {
    const float t = (float)(dd - 5);
    float w = 0.266011790f * exp2f(t * t * -0.32059890f);
    if (dd < 0 || dd > 10) w = 0.f;
    return w;
}

__global__ __launch_bounds__(256, 4) void ssim_band_kernel(
    const float* __restrict__ pred,
    const float* __restrict__ targ,
    float* __restrict__ out)
{
    const int tid = threadIdx.x;
    const int lane = tid & 63;
    const int wid = tid >> 6;              // 4 waves per block
    const int g = lane >> 4;               // MFMA k-quad group
    const int m = lane & 15;               // MFMA row/col index
    const int blk = blockIdx.x;
    const int plane = blk >> 4;            // 16 bands per plane
    const int band = blk & 15;
    const int r0 = band * BROWS;

    const float4* __restrict__ pp =
        (const float4*)(pred + (size_t)plane * (IMH * IMW));
    const float4* __restrict__ tp =
        (const float4*)(targ + (size_t)plane * (IMH * IMW));

    __shared__ __align__(16) char smem[SMEM_BYTES];
    __shared__ float wsum[WPB];

    const h2 M2 = splat16(-2.0f);
    const h2 Z16 = zero16();
    const h2 O16 = splat16(1.0f);

    // ---- Weight fragments, elem e: k = (e>>2)*16 + 4g + (e&3) ----
    // vertical B-frag: gw[k-m]; horizontal B-frag: gw[k-m-3] (pcol shift 8).
    half8 wfv, wfh;
    {
#pragma unroll
        for (int e = 0; e < 8; ++e) {
            const int k = (e >> 2) * 16 + 4 * g + (e & 3);
            wfv[e] = (_Float16)gweight(k - m);
            wfh[e] = (_Float16)gweight(k - m - 3);
        }
    }

    // ---- Stage: s,d planes col-major [col][k], k = 0..31 (rows r0-5..).
    // k >= 26 has all-zero weights -> skip the global load, write zeros.
#pragma unroll
    for (int q = 0; q < 2; ++q) {
        const int kq = wid * 8 + q * 4;
        h2 sA[4], sB[4], dA[4], dB[4];
#pragma unroll
        for (int dk = 0; dk < 4; ++dk) {
            const int k = kq + dk;
            const int r = r0 - RAD + k;
            const bool dead = (k >= 26);           // uniform per wave
            const bool zero = dead | (r < 0) | (r >= IMH);
            float4 a = make_float4(0.f, 0.f, 0.f, 0.f);
            float4 c = a;
            if (!dead) {
                const int rc = min(max(r, 0), IMH - 1);
                a = pp[rc * 64 + lane];
                c = tp[rc * 64 + lane];
            }
            const h2 x0 = clip_pack(a.x, a.y, Z16, O16);
            const h2 x1 = clip_pack(a.z, a.w, Z16, O16);
            const h2 y0 = clip_pack(c.x, c.y, Z16, O16);
            const h2 y1 = clip_pack(c.z, c.w, Z16, O16);
            h2 s0 = pk_add16(x0, y0);
            h2 s1 = pk_add16(x1, y1);
            h2 d0 = pk_fma16(M2, y0, s0);   // x - y
            h2 d1 = pk_fma16(M2, y1, s1);
            sA[dk] = zero ? Z16 : s0;
            sB[dk] = zero ? Z16 : s1;
            dA[dk] = zero ? Z16 : d0;
            dB[dk] = zero ? Z16 : d1;
        }
        // Repack rows->col-quads (v_perm) and write b64 per col per channel.
        char* const ws0 = smem + (size_t)(4 * lane) * CSTRIDE + kq * 2;
        char* const wd0 = ws0 + INPLANE;
        uint2 v;
        v.x = lo_pair(sA[0], sA[1]); v.y = lo_pair(sA[2], sA[3]);
        *(uint2*)(ws0 + 0 * CSTRIDE) = v;
        v.x = hi_pair(sA[0], sA[1]); v.y = hi_pair(sA[2], sA[3]);
        *(uint2*)(ws0 + 1 * CSTRIDE) = v;
        v.x = lo_pair(sB[0], sB[1]); v.y = lo_pair(sB[2], sB[3]);
        *(uint2*)(ws0 + 2 * CSTRIDE) = v;
        v.x = hi_pair(sB[0], sB[1]); v.y = hi_pair(sB[2], sB[3]);
        *(uint2*)(ws0 + 3 * CSTRIDE) = v;
        v.x = lo_pair(dA[0], dA[1]); v.y = lo_pair(dA[2], dA[3]);
        *(uint2*)(wd0 + 0 * CSTRIDE) = v;
        v.x = hi_pair(dA[0], dA[1]); v.y = hi_pair(dA[2], dA[3]);
        *(uint2*)(wd0 + 1 * CSTRIDE) = v;
        v.x = lo_pair(dB[0], dB[1]); v.y = lo_pair(dB[2], dB[3]);
        *(uint2*)(wd0 + 2 * CSTRIDE) = v;
        v.x = hi_pair(dB[0], dB[1]); v.y = hi_pair(dB[2], dB[3]);
        *(uint2*)(wd0 + 3 * CSTRIDE) = v;
    }
    __syncthreads();

    // ---- Vertical (TRANSPOSED): D^T = In^T x W^T via mfma(data, wfv).
    // A-frag (data): lane 16g+m holds In[k=4g+j][img col c0+m] -- the b64
    // reads at (c0+m)*72 + 8g (+32 hi), same addresses R19 validated.
    // D (m89): lane 16g+m holds V[img row m][img cols c0+4g+r], r=0..3.
    f32x4 Dv[4][4];                       // [tile][ch: s,d,s2,d2]
    const f32x4 z4 = {0.f, 0.f, 0.f, 0.f};
#pragma unroll
    for (int tt = 0; tt < 4; ++tt) {
        const int c0 = (wid * 4 + tt) * 16;
        const char* ps = smem + (size_t)(c0 + m) * CSTRIDE;
        const char* pd = ps + INPLANE;
        const half4 bs_lo = *(const half4*)(ps + 8 * g);
        const half4 bs_hi = *(const half4*)(ps + 32 + 8 * g);
        const half4 bd_lo = *(const half4*)(pd + 8 * g);
        const half4 bd_hi = *(const half4*)(pd + 32 + 8 * g);
        Dv[tt][0] = mfma32(cat8(bs_lo, bs_hi), wfv, z4);
        Dv[tt][1] = mfma32(cat8(bd_lo, bd_hi), wfv, z4);
        Dv[tt][2] = mfma32(cat8(sq4(bs_lo), sq4(bs_hi)), wfv, z4);
        Dv[tt][3] = mfma32(cat8(sq4(bd_lo), sq4(bd_hi)), wfv, z4);
    }
    __syncthreads();   // all input-plane reads done; region now reusable

    // ---- Write V planes row-major [row][pcol] f16 (reuse smem). ----
    // Lane 16g+m: row m, pcols 8+c0+4g .. +3 -> ONE aligned b64 per
    // (tile,ch): byte = m*552 + 2*(8+c0+4g) == 0 mod 8.
#pragma unroll
    for (int tt = 0; tt < 4; ++tt) {
        const int c0 = (wid * 4 + tt) * 16;
        const size_t pbase = (size_t)m * VROWSTRIDE + 2 * (8 + c0 + 4 * g);
#pragma unroll
        for (int ch = 0; ch < 4; ++ch) {
            uint2 w;
            w.x = pack2_rte(Dv[tt][ch][0], Dv[tt][ch][1]);
            w.y = pack2_rte(Dv[tt][ch][2], Dv[tt][ch][3]);
            *(uint2*)(smem + ch * VPLANE + pbase) = w;
        }
    }
    // Zero pads: pcol in {0..7} U {264..275}, 16 rows, 4 ch = 1280 u16
    // -> 5 scalar writes per thread (one-time).
#pragma unroll
    for (int e = 0; e < 5; ++e) {
        const int idx = tid + 256 * e;         // 0..1279
        const int ch = idx / 320;
        const int rem = idx - ch * 320;
        const int row = rem / 20;
        const int pc = rem - row * 20;
        const int p = pc < 8 ? pc : pc + 256;  // 0..7, 264..275
        *(__fp16*)(smem + ch * VPLANE + row * VROWSTRIDE + p * 2) =
            (__fp16)0.f;
    }
    __syncthreads();

    // ---- Horizontal + epilogue per tile (R19-validated structure). ----
    // A[m][k] = V[row m][pcol c0+k] -> aligned b64 at m*552 + 2*(c0+4g)
    // (+32 hi). B = wfh (gw[k-m-3]). D: lane 16g+m = img col c0+m,
    // rows 4g+r.
    const float C1 = 1e-4f, C2 = 9e-4f;
    float lsum = 0.f;
#pragma unroll
    for (int tt = 0; tt < 4; ++tt) {
        const int c0 = (wid * 4 + tt) * 16;
        const size_t abase = (size_t)m * VROWSTRIDE + 2 * (c0 + 4 * g);
        f32x4 D2[4];
#pragma unroll
        for (int ch = 0; ch < 4; ++ch) {
            const char* vb = smem + ch * VPLANE + abase;
            const half4 a_lo = *(const half4*)(vb);
            const half4 a_hi = *(const half4*)(vb + 32);
            D2[ch] = mfma32(cat8(a_lo, a_hi), wfh, z4);
        }
#pragma unroll
        for (int r = 0; r < 4; ++r) {
            const float ms = D2[0][r];
            const float md = D2[1][r];
            const float Ss = D2[2][r];
            const float Sd = D2[3][r];
            const float P = ms * ms, Q = md * md;
            const float mxy2 = 0.5f * (P - Q);            // 2*mx*my
            const float m2s  = 0.5f * (P + Q);            // mx^2+my^2
            const float Ssum = 0.5f * (Ss + Sd);          // Sxx+Syy
            const float ssum = fmaxf(Ssum - m2s, 0.f);    // vx+vy
            const float sxy2 = fmaf(0.5f, Ss - Sd, -mxy2); // 2*sigma_xy
            const float num = (mxy2 + C1) * (sxy2 + C2);
            const float den = fmaf(m2s + C1, ssum + C2, 1e-8f);
            lsum += num * __builtin_amdgcn_rcpf(den);
        }
    }

    // Wave reduction, 4-wave LDS combine, ONE atomic per block.
    // out starts at 0 (harness memset); final = 1 - sum/N via commutative
    // adds: every block adds -blocksum/N, block 0 also adds +1.0.
#pragma unroll
    for (int off = 32; off > 0; off >>= 1)
        lsum += __shfl_xor(lsum, off, 64);

    if (lane == 0) wsum[wid] = lsum;
    __syncthreads();
    if (tid == 0) {
        const float bsum = wsum[0] + wsum[1] + wsum[2] + wsum[3];
        float contrib = bsum * (-1.0f / NPIXF);
        if (blk == 0) contrib += 1.0f;
        atomicAdd(out, contrib);
    }
}

extern "C" void kernel_launch(void* const* d_in, const int* in_sizes, int n_in,
                              void* d_out, int out_size, void* d_ws, size_t ws_size,
                              hipStream_t stream) {
    const float* pred = (const float*)d_in[0];
    const float* targ = (const float*)d_in[1];
    float* out = (float*)d_out;
    (void)d_ws; (void)ws_size;

    ssim_band_kernel<<<NGRID, 256, 0, stream>>>(pred, targ, out);
}